// Round 6
// baseline (4001.149 us; speedup 1.0000x reference)
//
#include <hip/hip_runtime.h>

// PointNet++ forward (B=8, N=4096, D=2, F=5)
// sa1: FPS 4096->2048, r=0.2, MLP 7->32->64
// sa2: FPS 2048->512,  r=0.4, MLP 66->64->128
// sa3: MLP 130->128->256, global max
// head: MLP 256->256->1024
//
// Discrete selections (FPS argmax, top-64 neighbor sets) are reproduced
// bit-exactly vs XLA: distances use mul/mul/add (no FMA contraction; pk ops
// are per-element IEEE rne), argmax = first max, top_k ties = lowest index.

typedef float v2f __attribute__((ext_vector_type(2)));

__device__ __forceinline__ v2f pk_add(v2f a, v2f b) {
  v2f r; asm("v_pk_add_f32 %0, %1, %2" : "=v"(r) : "v"(a), "v"(b)); return r;
}
__device__ __forceinline__ v2f pk_mul(v2f a, v2f b) {
  v2f r; asm("v_pk_mul_f32 %0, %1, %2" : "=v"(r) : "v"(a), "v"(b)); return r;
}

#define DPP_UMAX(u, ctrl)                                                      \
  do {                                                                         \
    unsigned _o = (unsigned)__builtin_amdgcn_update_dpp(0, (int)(u), (ctrl),   \
                                                        0xf, 0xf, true);       \
    (u) = ((u) > _o) ? (u) : _o;                                               \
  } while (0)

// 64-bit-key max with 8-byte coord payload; key = (dist_bits<<32) | ~wave_id
// so dist ties pick the LOWEST wave (= lowest point indices, since waves own
// ascending contiguous index ranges).
__device__ __forceinline__ uint4 kmax4(uint4 a, uint4 b) {
  unsigned long long ka = ((unsigned long long)a.y << 32) | a.x;
  unsigned long long kb = ((unsigned long long)b.y << 32) | b.x;
  bool c = kb > ka;
  uint4 r;
  r.x = c ? b.x : a.x; r.y = c ? b.y : a.y;
  r.z = c ? b.z : a.z; r.w = c ? b.w : a.w;
  return r;
}

// One FPS stage. Points live ONLY in registers as v2f pairs (lane-contiguous:
// point = t*PPT + k). Distance update uses packed-f32 VALU (2 pts/inst);
// per-lane argmax is a depth-log2(PPT) tree carrying (val,x,y); winner coords
// travel in the exchange payload. Exact first-max semantics: within-lane
// ordered tree, within-wave first-lane (ballot+ctz), across-wave lowest wave
// via ~wave_id in the key.
template<int PPT, int T>
__device__ __forceinline__ void fps_stage(
    v2f (&xv)[PPT / 2], v2f (&yv)[PPT / 2], int Msel, int t,
    float lx, float ly,
    float* wlx, float* wly,              // LDS winner list (this stage)
    uint4* slots /*[2*NW]*/) {
  constexpr int NW = T / 64;
  constexpr int NV = PPT / 2;
  const int wvid = t >> 6;
  v2f d2[NV];
#pragma unroll
  for (int j = 0; j < NV; ++j) { d2[j].x = 1e9f; d2[j].y = 1e9f; }

  for (int i = 1; i < Msel; ++i) {
    // packed distance update: dx=x+(-lx), dy=y+(-ly), dd=dx*dx + dy*dy (rne,
    // no contraction), d=min(d,dd). Bit-exact vs scalar mul/mul/add.
    v2f mlx, mly;
    mlx.x = -lx; mlx.y = -lx; mly.x = -ly; mly.y = -ly;
#pragma unroll
    for (int j = 0; j < NV; ++j) {
      v2f dx = pk_add(xv[j], mlx);
      v2f dy = pk_add(yv[j], mly);
      v2f dd = pk_add(pk_mul(dx, dx), pk_mul(dy, dy));
      d2[j].x = fminf(d2[j].x, dd.x);
      d2[j].y = fminf(d2[j].y, dd.y);
    }
    // per-lane first-argmax tree with (val,x,y) payload, depth log2(PPT)
    float tv[NV], tx[NV], ty[NV];
#pragma unroll
    for (int j = 0; j < NV; ++j) {      // leaf pair: k=2j vs k=2j+1
      bool c = d2[j].y > d2[j].x;
      tv[j] = c ? d2[j].y : d2[j].x;
      tx[j] = c ? xv[j].y : xv[j].x;
      ty[j] = c ? yv[j].y : yv[j].x;
    }
#pragma unroll
    for (int w = NV / 2; w >= 1; w >>= 1) {
#pragma unroll
      for (int j = 0; j < w; ++j) {     // right group = higher k: strict >
        bool c = tv[j + w] > tv[j];
        tv[j] = c ? tv[j + w] : tv[j];
        tx[j] = c ? tx[j + w] : tx[j];
        ty[j] = c ? ty[j + w] : ty[j];
      }
    }
    const float bv = tv[0], bx = tx[0], by = ty[0];
    // wave-level value max via DPP (VALU pipe)
    const unsigned mybits = __float_as_uint(bv);
    unsigned u = mybits;
    DPP_UMAX(u, 0x111);  // row_shr:1
    DPP_UMAX(u, 0x112);  // row_shr:2
    DPP_UMAX(u, 0x114);  // row_shr:4
    DPP_UMAX(u, 0x118);  // row_shr:8
    DPP_UMAX(u, 0x142);  // row_bcast:15
    DPP_UMAX(u, 0x143);  // row_bcast:31 -> lane63 = wave max
    const unsigned wvb = (unsigned)__builtin_amdgcn_readlane((int)u, 63);
    const unsigned long long tmask = __ballot(mybits == wvb);
    const int fl = (int)__builtin_ctzll(tmask);  // first lane = smallest idx
    const int par = i & 1;
    if ((t & 63) == fl)                          // winning lane writes payload
      slots[par * NW + wvid] = make_uint4(~(unsigned)wvid, wvb,
                                          __float_as_uint(bx),
                                          __float_as_uint(by));
    __syncthreads();
    // cross-wave compare tree on payload slots (broadcast reads, no conflict)
    const uint4* sl = &slots[par * NW];
    uint4 arr[NW];
#pragma unroll
    for (int j = 0; j < NW; ++j) arr[j] = sl[j];
#pragma unroll
    for (int s = NW / 2; s >= 1; s >>= 1)
#pragma unroll
      for (int j = 0; j < s; ++j) arr[j] = kmax4(arr[j], arr[j + s]);
    lx = __uint_as_float(arr[0].z);
    ly = __uint_as_float(arr[0].w);
    if (t == 0) { wlx[i] = lx; wly[i] = ly; }
    // no 2nd barrier: slots double-buffered by parity
  }
}

// Fused fps1 (N->M1) + fps2 (M1->M2); one block per batch, T=256 (4 waves).
template<int N, int M1, int M2, int T>
__global__ __launch_bounds__(T, 1) void fps_fused_kernel(
    const float* __restrict__ pos,    // [B][N][2]
    float* __restrict__ posq1,        // [B][M1][2]
    float* __restrict__ posq2) {      // [B][M2][2]
  constexpr int PPT  = N / T;
  constexpr int PPT2 = M1 / T;
  constexpr int NW   = T / 64;
  __shared__ float wlx[M1], wly[M1];      // stage-1 winners = stage-2 points
  __shared__ float wl2x[M2], wl2y[M2];    // stage-2 winners
  __shared__ uint4 slots[2 * NW];
  const int b = blockIdx.x, t = threadIdx.x;
  v2f xv[PPT / 2], yv[PPT / 2];
  const float4* p4 = (const float4*)(pos + (size_t)b * N * 2 + (size_t)t * PPT * 2);
#pragma unroll
  for (int q = 0; q < PPT / 2; ++q) {
    float4 v = p4[q];
    xv[q].x = v.x; yv[q].x = v.y;
    xv[q].y = v.z; yv[q].y = v.w;
  }
  if (t == 0) { wlx[0] = xv[0].x; wly[0] = yv[0].x; }   // first winner = pt 0
  __syncthreads();
  float lx = wlx[0], ly = wly[0];
  fps_stage<PPT, T>(xv, yv, M1, t, lx, ly, wlx, wly, slots);
  __syncthreads();                       // winner list complete
  for (int j = t; j < M1; j += T)        // bulk coalesced posq1
    ((float2*)posq1)[(size_t)b * M1 + j] = make_float2(wlx[j], wly[j]);
  v2f x2[PPT2 / 2], y2[PPT2 / 2];
#pragma unroll
  for (int k = 0; k < PPT2 / 2; ++k) {
    x2[k].x = wlx[t * PPT2 + 2 * k];     y2[k].x = wly[t * PPT2 + 2 * k];
    x2[k].y = wlx[t * PPT2 + 2 * k + 1]; y2[k].y = wly[t * PPT2 + 2 * k + 1];
  }
  float lx2 = wlx[0], ly2 = wly[0];      // stage-2 first winner = wl[0]
  if (t == 0) { wl2x[0] = lx2; wl2y[0] = ly2; }
  fps_stage<PPT2, T>(x2, y2, M2, t, lx2, ly2, wl2x, wl2y, slots);
  __syncthreads();
  for (int j = t; j < M2; j += T)
    ((float2*)posq2)[(size_t)b * M2 + j] = make_float2(wl2x[j], wl2y[j]);
}

// ------------------------------------------------- radius top-64 neighbors
// One wave per query. Exact set of <=64 nearest in-radius points,
// matching lax.top_k(-d2) with lowest-index tie-break.
template<int CPL>   // candidate points per lane = NPTS/64
__global__ __launch_bounds__(256) void nbr_kernel(
    const float* __restrict__ pts,   // [B][NPTS][2]
    const float* __restrict__ posq,  // [total_q][2]
    int* __restrict__ nbr,           // [total_q][64], -1 = invalid
    int M, int NPTS, int total_q, float R2) {
  const int wid = blockIdx.x * 4 + (threadIdx.x >> 6);
  if (wid >= total_q) return;
  const int lane = threadIdx.x & 63;
  const int b = wid / M;
  const float qx = posq[(size_t)wid * 2 + 0], qy = posq[(size_t)wid * 2 + 1];
  const float* p = pts + (size_t)b * NPTS * 2;
  unsigned bits[CPL];
  int cnt = 0;
#pragma unroll
  for (int k = 0; k < CPL; ++k) {
    int pt = lane + (k << 6);
    float dx = p[pt * 2 + 0] - qx, dy = p[pt * 2 + 1] - qy;
    float dd = __fadd_rn(__fmul_rn(dx, dx), __fmul_rn(dy, dy));  // exact
    bool inr = (dd <= R2);
    bits[k] = inr ? __float_as_uint(dd) : 0xFFFFFFFFu;
    cnt += __popcll(__ballot(inr));
  }
  const unsigned long long below = (1ULL << lane) - 1ULL;
  if (cnt <= 64) {
    int base = 0;
#pragma unroll
    for (int k = 0; k < CPL; ++k) {
      bool s = (bits[k] != 0xFFFFFFFFu);
      unsigned long long m = __ballot(s);
      if (s) nbr[(size_t)wid * 64 + base + __popcll(m & below)] = lane + (k << 6);
      base += __popcll(m);
    }
    for (int j = base + lane; j < 64; j += 64) nbr[(size_t)wid * 64 + j] = -1;
  } else {
    // bisection on float bit pattern for exact 64th smallest d2
    unsigned lo = 0, hi = __float_as_uint(R2);
    while (lo < hi) {
      unsigned mid = lo + ((hi - lo) >> 1);
      int c = 0;
#pragma unroll
      for (int k = 0; k < CPL; ++k) c += __popcll(__ballot(bits[k] <= mid));
      if (c >= 64) hi = mid; else lo = mid + 1;
    }
    int cless = 0;
#pragma unroll
    for (int k = 0; k < CPL; ++k) cless += __popcll(__ballot(bits[k] < lo));
    const int need = 64 - cless;     // ties to take at cutoff, ascending index
    int base = 0, tiecnt = 0;
#pragma unroll
    for (int k = 0; k < CPL; ++k) {
      bool tie = (bits[k] == lo);
      unsigned long long tm = __ballot(tie);
      bool s = (bits[k] < lo) || (tie && (tiecnt + __popcll(tm & below)) < need);
      tiecnt += __popcll(tm);
      unsigned long long m = __ballot(s);
      if (s) nbr[(size_t)wid * 64 + base + __popcll(m & below)] = lane + (k << 6);
      base += __popcll(m);
    }
    // base == 64 exactly; no fill needed
  }
}

// ------------------------------------------------------------ PointConv
// Wave per query. Phase B: lane = neighbor, compute hidden (W1t broadcast
// from LDS). Phase C: transpose hidden into LDS. Phase D: lane = out channel,
// W2 column in VGPRs, max over neighbors is lane-local (no cross-lane reduce).
template<int CIN, int H, int COUT, int QPB, int NPTS, int HS, int W1P>
__global__ __launch_bounds__(64 * QPB) void conv_kernel(
    const float* __restrict__ x,     // [B][NPTS][CIN]
    const float* __restrict__ pts,   // [B][NPTS][2]
    const float* __restrict__ posq,  // [total_q][2]
    const int* __restrict__ nbr,     // [total_q][64]
    const float* __restrict__ W1, const float* __restrict__ b1,   // [CIN+2][H],[H]
    const float* __restrict__ W2, const float* __restrict__ b2,   // [H][COUT],[COUT]
    float* __restrict__ out,         // [total_q][COUT]
    int M) {
  constexpr int CI2 = CIN + 2;
  __shared__ float sW1t[H * W1P];    // transposed: [H][CI2 padded]
  __shared__ float sB1[H];
  __shared__ float sHH[QPB * 64 * HS];
  const int tid = threadIdx.x;
  for (int j = tid; j < CI2 * H; j += 64 * QPB) {
    int c = j / H, h = j - c * H;
    sW1t[h * W1P + c] = W1[j];
  }
  for (int j = tid; j < H; j += 64 * QPB) sB1[j] = b1[j];
  __syncthreads();
  const int wv = tid >> 6, lane = tid & 63;
  const int wid = blockIdx.x * QPB + wv;
  const int b = wid / M;
  // Phase A: gather neighbor features + relative position
  const int idx = nbr[(size_t)wid * 64 + lane];
  const unsigned long long vm = __ballot(idx >= 0);
  const int ii = (idx < 0) ? 0 : idx;
  float in[CI2];
  {
    const float* xp = x + ((size_t)b * NPTS + ii) * CIN;
#pragma unroll
    for (int c = 0; c < CIN; ++c) in[c] = xp[c];
    float qx = posq[(size_t)wid * 2 + 0], qy = posq[(size_t)wid * 2 + 1];
    const float* pp = pts + ((size_t)b * NPTS + ii) * 2;
    in[CIN] = pp[0] - qx;
    in[CIN + 1] = pp[1] - qy;
  }
  // Phase B+C: hidden layer + transpose to LDS (wave-local, no barrier needed)
  float* hbase = &sHH[wv * 64 * HS];
#pragma unroll
  for (int h = 0; h < H; h += 4) {
    float vv[4];
#pragma unroll
    for (int j = 0; j < 4; ++j) {
      float a = sB1[h + j];
#pragma unroll
      for (int c = 0; c < CI2; ++c) a = fmaf(in[c], sW1t[(h + j) * W1P + c], a);
      vv[j] = fmaxf(a, 0.0f);
    }
    *(float4*)&hbase[lane * HS + h] = make_float4(vv[0], vv[1], vv[2], vv[3]);
  }
  // Phase D: second layer + masked max over neighbors
#pragma unroll
  for (int half = 0; half < COUT / 64; ++half) {
    const int o = half * 64 + lane;
    float w2r[H];
#pragma unroll
    for (int h = 0; h < H; ++h) w2r[h] = W2[h * COUT + o];
    const float b2o = b2[o];
    float m = -1e30f;
    for (int n = 0; n < 64; ++n) {
      const float4* hp = (const float4*)&hbase[n * HS];
      float a = b2o;
#pragma unroll
      for (int j = 0; j < H / 4; ++j) {
        float4 hv = hp[j];
        a = fmaf(hv.x, w2r[4 * j + 0], a);
        a = fmaf(hv.y, w2r[4 * j + 1], a);
        a = fmaf(hv.z, w2r[4 * j + 2], a);
        a = fmaf(hv.w, w2r[4 * j + 3], a);
      }
      a = ((vm >> n) & 1ULL) ? a : -1e9f;   // masked like reference (-BIG)
      m = fmaxf(m, a);
    }
    out[(size_t)wid * COUT + o] = m;
  }
}

// ---------------------------------------------------- global MLP (layer a)
__global__ __launch_bounds__(256) void u_kernel(
    const float* __restrict__ h2,     // [4096][128]
    const float* __restrict__ posq2,  // [4096][2]
    const float* __restrict__ W3a, const float* __restrict__ b3a,
    float* __restrict__ u) {          // [4096][128]
  const int p = blockIdx.x * 2 + (threadIdx.x >> 7);
  const int h = threadIdx.x & 127;
  const float* hp = h2 + (size_t)p * 128;
  float a = b3a[h];
  for (int c = 0; c < 128; ++c) a = fmaf(hp[c], W3a[c * 128 + h], a);
  a = fmaf(posq2[(size_t)p * 2 + 0], W3a[128 * 128 + h], a);
  a = fmaf(posq2[(size_t)p * 2 + 1], W3a[129 * 128 + h], a);
  u[(size_t)p * 128 + h] = fmaxf(a, 0.0f);
}

// ---------------------------------- global MLP (layer b) + partial max-pool
__global__ __launch_bounds__(256) void g_kernel(
    const float* __restrict__ u,      // [4096][128]
    const float* __restrict__ W3b, const float* __restrict__ b3b,
    float* __restrict__ part) {       // [64][256]
  __shared__ float su[64 * 128];
  const int bb = blockIdx.x;          // chunk of 64 consecutive points
  const float* up = u + (size_t)bb * 64 * 128;
  for (int j = threadIdx.x; j < 64 * 128; j += 256) su[j] = up[j];
  __syncthreads();
  const int o = threadIdx.x;
  float w[128];
#pragma unroll
  for (int h = 0; h < 128; ++h) w[h] = W3b[h * 256 + o];
  float m = -1e30f;
  for (int p = 0; p < 64; ++p) {
    float a = b3b[o];
    const float4* sp = (const float4*)&su[p * 128];
#pragma unroll
    for (int j = 0; j < 32; ++j) {
      float4 v = sp[j];
      a = fmaf(v.x, w[4 * j + 0], a);
      a = fmaf(v.y, w[4 * j + 1], a);
      a = fmaf(v.z, w[4 * j + 2], a);
      a = fmaf(v.w, w[4 * j + 3], a);
    }
    m = fmaxf(m, a);
  }
  part[(size_t)bb * 256 + o] = m;
}

// ------------------------------------------------------------------ head
__global__ __launch_bounds__(256) void head_kernel(
    const float* __restrict__ part,   // [64][256] (8 chunks per batch)
    const float* __restrict__ W4a, const float* __restrict__ b4a,
    const float* __restrict__ W4b, const float* __restrict__ b4b,
    float* __restrict__ out) {        // [8][1024]
  __shared__ float g[256], h4[256];
  const int b = blockIdx.x, t = threadIdx.x;
  float m = part[(size_t)(b * 8 + 0) * 256 + t];
  for (int c = 1; c < 8; ++c) m = fmaxf(m, part[(size_t)(b * 8 + c) * 256 + t]);
  g[t] = m;
  __syncthreads();
  float a = b4a[t];
  for (int c = 0; c < 256; ++c) a = fmaf(g[c], W4a[c * 256 + t], a);
  h4[t] = fmaxf(a, 0.0f);
  __syncthreads();
  for (int jj = 0; jj < 4; ++jj) {
    int o = t + jj * 256;
    float a2 = b4b[o];
    for (int c = 0; c < 256; ++c) a2 = fmaf(h4[c], W4b[c * 1024 + o], a2);
    out[(size_t)b * 1024 + o] = a2;
  }
}

// ------------------------------------------------------------------ launch
extern "C" void kernel_launch(void* const* d_in, const int* in_sizes, int n_in,
                              void* d_out, int out_size, void* d_ws, size_t ws_size,
                              hipStream_t stream) {
  (void)in_sizes; (void)n_in; (void)out_size; (void)ws_size;
  const float* x   = (const float*)d_in[0];
  const float* pos = (const float*)d_in[1];
  const float* w1a = (const float*)d_in[2];  const float* b1a = (const float*)d_in[3];
  const float* w1b = (const float*)d_in[4];  const float* b1b = (const float*)d_in[5];
  const float* w2a = (const float*)d_in[6];  const float* b2a = (const float*)d_in[7];
  const float* w2b = (const float*)d_in[8];  const float* b2b = (const float*)d_in[9];
  const float* w3a = (const float*)d_in[10]; const float* b3a = (const float*)d_in[11];
  const float* w3b = (const float*)d_in[12]; const float* b3b = (const float*)d_in[13];
  const float* w4a = (const float*)d_in[14]; const float* b4a = (const float*)d_in[15];
  const float* w4b = (const float*)d_in[16]; const float* b4b = (const float*)d_in[17];
  float* outp = (float*)d_out;

  char* ws = (char*)d_ws;
  size_t off = 0;
  float* posq1 = (float*)(ws + off); off += (size_t)8 * 2048 * 2 * 4;   // 128 KB
  float* posq2 = (float*)(ws + off); off += (size_t)8 * 512 * 2 * 4;    //  32 KB
  int*   nbr1  = (int*)  (ws + off); off += (size_t)16384 * 64 * 4;     //   4 MB
  int*   nbr2  = (int*)  (ws + off); off += (size_t)4096 * 64 * 4;      //   1 MB
  float* h1    = (float*)(ws + off); off += (size_t)16384 * 64 * 4;     //   4 MB
  float* h2    = (float*)(ws + off); off += (size_t)4096 * 128 * 4;     //   2 MB
  float* u3    = (float*)(ws + off); off += (size_t)4096 * 128 * 4;     //   2 MB
  float* part  = (float*)(ws + off); off += (size_t)64 * 256 * 4;       //  64 KB

  fps_fused_kernel<4096, 2048, 512, 256><<<dim3(8), dim3(256), 0, stream>>>(
      pos, posq1, posq2);
  nbr_kernel<64><<<dim3(4096), dim3(256), 0, stream>>>(pos, posq1, nbr1,
                                                       2048, 4096, 16384, 0.04f);
  conv_kernel<5, 32, 64, 4, 4096, 36, 8><<<dim3(4096), dim3(256), 0, stream>>>(
      x, pos, posq1, nbr1, w1a, b1a, w1b, b1b, h1, 2048);
  nbr_kernel<32><<<dim3(1024), dim3(256), 0, stream>>>(posq1, posq2, nbr2,
                                                       512, 2048, 4096, 0.16f);
  conv_kernel<64, 64, 128, 2, 2048, 68, 68><<<dim3(2048), dim3(128), 0, stream>>>(
      h1, posq1, posq2, nbr2, w2a, b2a, w2b, b2b, h2, 512);
  u_kernel<<<dim3(2048), dim3(256), 0, stream>>>(h2, posq2, w3a, b3a, u3);
  g_kernel<<<dim3(64), dim3(256), 0, stream>>>(u3, w3b, b3b, part);
  head_kernel<<<dim3(8), dim3(256), 0, stream>>>(part, w4a, b4a, w4b, b4b, outp);
}

// Round 7
// 2330.704 us; speedup vs baseline: 1.7167x; 1.7167x over previous
//
#include <hip/hip_runtime.h>

// PointNet++ forward (B=8, N=4096, D=2, F=5)
// sa1: FPS 4096->2048, r=0.2, MLP 7->32->64
// sa2: FPS 2048->512,  r=0.4, MLP 66->64->128
// sa3: MLP 130->128->256, global max
// head: MLP 256->256->1024
//
// Discrete selections (FPS argmax, top-64 neighbor sets) are reproduced
// bit-exactly vs XLA: distances use __fmul_rn/__fadd_rn (no FMA contraction),
// argmax = first max, top_k ties = lowest index first.

#define DPP_UMAX(u, ctrl)                                                      \
  do {                                                                         \
    unsigned _o = (unsigned)__builtin_amdgcn_update_dpp(0, (int)(u), (ctrl),   \
                                                        0xf, 0xf, true);       \
    (u) = ((u) > _o) ? (u) : _o;                                               \
  } while (0)

// 64-bit-key max with 8-byte coord payload; key = (dist_bits<<32) | ~wave_id
// so dist ties pick the LOWEST wave (= lowest point indices, since waves own
// ascending contiguous index ranges).
__device__ __forceinline__ uint4 kmax4(uint4 a, uint4 b) {
  unsigned long long ka = ((unsigned long long)a.y << 32) | a.x;
  unsigned long long kb = ((unsigned long long)b.y << 32) | b.x;
  bool c = kb > ka;
  uint4 r;
  r.x = c ? b.x : a.x; r.y = c ? b.y : a.y;
  r.z = c ? b.z : a.z; r.w = c ? b.w : a.w;
  return r;
}

// One FPS stage. Points live ONLY in registers (lane-contiguous: point =
// t*PPT+k). Winner coords are tracked through the select chain and travel in
// the exchange payload -> no LDS mirror, no scattered reads, no readlanes.
// Exact first-max semantics: within-lane first-k, within-wave first-lane
// (ballot+ctz), across-wave lowest wave via ~wave_id in the key.
template<int PPT, int T>
__device__ __forceinline__ void fps_stage(
    float (&xr)[PPT], float (&yr)[PPT], int Msel, int t,
    float lx, float ly,
    float* wlx, float* wly,              // LDS winner list (this stage)
    uint4* slots /*[2*NW]*/) {
  constexpr int NW = T / 64;
  constexpr int HP = PPT / 2;
  const int wvid = t >> 6;
  float d[PPT];
#pragma unroll
  for (int k = 0; k < PPT; ++k) d[k] = 1e9f;

  for (int i = 1; i < Msel; ++i) {
    // distance update (exact: mul/mul/add, no fma)
#pragma unroll
    for (int k = 0; k < PPT; ++k) {
      float dx = xr[k] - lx, dy = yr[k] - ly;
      float dd = __fadd_rn(__fmul_rn(dx, dx), __fmul_rn(dy, dy));
      d[k] = fminf(d[k], dd);
    }
    // per-lane first-argmax with coord payload: two independent half-chains
    float bvA = d[0],  bxA = xr[0],  byA = yr[0];
    float bvB = d[HP], bxB = xr[HP], byB = yr[HP];
#pragma unroll
    for (int k = 1; k < HP; ++k) {
      if (d[k] > bvA)      { bvA = d[k];      bxA = xr[k];      byA = yr[k]; }
      if (d[HP + k] > bvB) { bvB = d[HP + k]; bxB = xr[HP + k]; byB = yr[HP + k]; }
    }
    float bv = bvA, bx = bxA, by = byA;
    if (bvB > bvA) { bv = bvB; bx = bxB; by = byB; }  // tie keeps A = lower idx
    // wave-level value max via DPP (VALU pipe)
    const unsigned mybits = __float_as_uint(bv);
    unsigned u = mybits;
    DPP_UMAX(u, 0x111);  // row_shr:1
    DPP_UMAX(u, 0x112);  // row_shr:2
    DPP_UMAX(u, 0x114);  // row_shr:4
    DPP_UMAX(u, 0x118);  // row_shr:8
    DPP_UMAX(u, 0x142);  // row_bcast:15
    DPP_UMAX(u, 0x143);  // row_bcast:31 -> lane63 = wave max
    const unsigned wvb = (unsigned)__builtin_amdgcn_readlane((int)u, 63);
    const unsigned long long tmask = __ballot(mybits == wvb);
    const int fl = (int)__builtin_ctzll(tmask);  // first lane = smallest idx
    const int par = i & 1;
    if ((t & 63) == fl)                          // winning lane writes payload
      slots[par * NW + wvid] = make_uint4(~(unsigned)wvid, wvb,
                                          __float_as_uint(bx),
                                          __float_as_uint(by));
    __syncthreads();
    // cross-wave compare tree on payload slots (broadcast reads, no conflict)
    const uint4* sl = &slots[par * NW];
    uint4 arr[NW];
#pragma unroll
    for (int j = 0; j < NW; ++j) arr[j] = sl[j];
#pragma unroll
    for (int s = NW / 2; s >= 1; s >>= 1)
#pragma unroll
      for (int j = 0; j < s; ++j) arr[j] = kmax4(arr[j], arr[j + s]);
    lx = __uint_as_float(arr[0].z);
    ly = __uint_as_float(arr[0].w);
    if (t == 0) { wlx[i] = lx; wly[i] = ly; }
    // no 2nd barrier: slots double-buffered by parity
  }
}

// Fused fps1 (N->M1) + fps2 (M1->M2); one block per batch, T=512 (8 waves).
template<int N, int M1, int M2, int T>
__global__ __launch_bounds__(T, 1) void fps_fused_kernel(
    const float* __restrict__ pos,    // [B][N][2]
    float* __restrict__ posq1,        // [B][M1][2]
    float* __restrict__ posq2) {      // [B][M2][2]
  constexpr int PPT  = N / T;
  constexpr int PPT2 = M1 / T;
  constexpr int NW   = T / 64;
  __shared__ float wlx[M1], wly[M1];      // stage-1 winners = stage-2 points
  __shared__ float wl2x[M2], wl2y[M2];    // stage-2 winners
  __shared__ uint4 slots[2 * NW];
  const int b = blockIdx.x, t = threadIdx.x;
  float xr[PPT], yr[PPT];
  const float4* p4 = (const float4*)(pos + (size_t)b * N * 2 + (size_t)t * PPT * 2);
#pragma unroll
  for (int q = 0; q < PPT / 2; ++q) {
    float4 v = p4[q];
    xr[2 * q + 0] = v.x; yr[2 * q + 0] = v.y;
    xr[2 * q + 1] = v.z; yr[2 * q + 1] = v.w;
  }
  if (t == 0) { wlx[0] = xr[0]; wly[0] = yr[0]; }   // first winner = point 0
  __syncthreads();
  float lx = wlx[0], ly = wly[0];
  fps_stage<PPT, T>(xr, yr, M1, t, lx, ly, wlx, wly, slots);
  __syncthreads();                       // winner list complete
  for (int j = t; j < M1; j += T)        // bulk coalesced posq1
    ((float2*)posq1)[(size_t)b * M1 + j] = make_float2(wlx[j], wly[j]);
  float x2[PPT2], y2[PPT2];
#pragma unroll
  for (int k = 0; k < PPT2; ++k) { x2[k] = wlx[t * PPT2 + k]; y2[k] = wly[t * PPT2 + k]; }
  float lx2 = wlx[0], ly2 = wly[0];      // stage-2 first winner = wl[0]
  if (t == 0) { wl2x[0] = lx2; wl2y[0] = ly2; }
  fps_stage<PPT2, T>(x2, y2, M2, t, lx2, ly2, wl2x, wl2y, slots);
  __syncthreads();
  for (int j = t; j < M2; j += T)
    ((float2*)posq2)[(size_t)b * M2 + j] = make_float2(wl2x[j], wl2y[j]);
}

// ------------------------------------------------- radius top-64 neighbors
// One wave per query. Exact set of <=64 nearest in-radius points,
// matching lax.top_k(-d2) with lowest-index tie-break.
template<int CPL>   // candidate points per lane = NPTS/64
__global__ __launch_bounds__(256) void nbr_kernel(
    const float* __restrict__ pts,   // [B][NPTS][2]
    const float* __restrict__ posq,  // [total_q][2]
    int* __restrict__ nbr,           // [total_q][64], -1 = invalid
    int M, int NPTS, int total_q, float R2) {
  const int wid = blockIdx.x * 4 + (threadIdx.x >> 6);
  if (wid >= total_q) return;
  const int lane = threadIdx.x & 63;
  const int b = wid / M;
  const float qx = posq[(size_t)wid * 2 + 0], qy = posq[(size_t)wid * 2 + 1];
  const float* p = pts + (size_t)b * NPTS * 2;
  unsigned bits[CPL];
  int cnt = 0;
#pragma unroll
  for (int k = 0; k < CPL; ++k) {
    int pt = lane + (k << 6);
    float dx = p[pt * 2 + 0] - qx, dy = p[pt * 2 + 1] - qy;
    float dd = __fadd_rn(__fmul_rn(dx, dx), __fmul_rn(dy, dy));  // exact
    bool inr = (dd <= R2);
    bits[k] = inr ? __float_as_uint(dd) : 0xFFFFFFFFu;
    cnt += __popcll(__ballot(inr));
  }
  const unsigned long long below = (1ULL << lane) - 1ULL;
  if (cnt <= 64) {
    int base = 0;
#pragma unroll
    for (int k = 0; k < CPL; ++k) {
      bool s = (bits[k] != 0xFFFFFFFFu);
      unsigned long long m = __ballot(s);
      if (s) nbr[(size_t)wid * 64 + base + __popcll(m & below)] = lane + (k << 6);
      base += __popcll(m);
    }
    for (int j = base + lane; j < 64; j += 64) nbr[(size_t)wid * 64 + j] = -1;
  } else {
    // bisection on float bit pattern for exact 64th smallest d2
    unsigned lo = 0, hi = __float_as_uint(R2);
    while (lo < hi) {
      unsigned mid = lo + ((hi - lo) >> 1);
      int c = 0;
#pragma unroll
      for (int k = 0; k < CPL; ++k) c += __popcll(__ballot(bits[k] <= mid));
      if (c >= 64) hi = mid; else lo = mid + 1;
    }
    int cless = 0;
#pragma unroll
    for (int k = 0; k < CPL; ++k) cless += __popcll(__ballot(bits[k] < lo));
    const int need = 64 - cless;     // ties to take at cutoff, ascending index
    int base = 0, tiecnt = 0;
#pragma unroll
    for (int k = 0; k < CPL; ++k) {
      bool tie = (bits[k] == lo);
      unsigned long long tm = __ballot(tie);
      bool s = (bits[k] < lo) || (tie && (tiecnt + __popcll(tm & below)) < need);
      tiecnt += __popcll(tm);
      unsigned long long m = __ballot(s);
      if (s) nbr[(size_t)wid * 64 + base + __popcll(m & below)] = lane + (k << 6);
      base += __popcll(m);
    }
    // base == 64 exactly; no fill needed
  }
}

// ------------------------------------------------------------ PointConv
// Wave per query. Phase B: lane = neighbor, compute hidden (W1t broadcast
// from LDS). Phase C: transpose hidden into LDS. Phase D: lane = out channel,
// W2 column in VGPRs, max over neighbors is lane-local (no cross-lane reduce).
template<int CIN, int H, int COUT, int QPB, int NPTS, int HS, int W1P>
__global__ __launch_bounds__(64 * QPB) void conv_kernel(
    const float* __restrict__ x,     // [B][NPTS][CIN]
    const float* __restrict__ pts,   // [B][NPTS][2]
    const float* __restrict__ posq,  // [total_q][2]
    const int* __restrict__ nbr,     // [total_q][64]
    const float* __restrict__ W1, const float* __restrict__ b1,   // [CIN+2][H],[H]
    const float* __restrict__ W2, const float* __restrict__ b2,   // [H][COUT],[COUT]
    float* __restrict__ out,         // [total_q][COUT]
    int M) {
  constexpr int CI2 = CIN + 2;
  __shared__ float sW1t[H * W1P];    // transposed: [H][CI2 padded]
  __shared__ float sB1[H];
  __shared__ float sHH[QPB * 64 * HS];
  const int tid = threadIdx.x;
  for (int j = tid; j < CI2 * H; j += 64 * QPB) {
    int c = j / H, h = j - c * H;
    sW1t[h * W1P + c] = W1[j];
  }
  for (int j = tid; j < H; j += 64 * QPB) sB1[j] = b1[j];
  __syncthreads();
  const int wv = tid >> 6, lane = tid & 63;
  const int wid = blockIdx.x * QPB + wv;
  const int b = wid / M;
  // Phase A: gather neighbor features + relative position
  const int idx = nbr[(size_t)wid * 64 + lane];
  const unsigned long long vm = __ballot(idx >= 0);
  const int ii = (idx < 0) ? 0 : idx;
  float in[CI2];
  {
    const float* xp = x + ((size_t)b * NPTS + ii) * CIN;
#pragma unroll
    for (int c = 0; c < CIN; ++c) in[c] = xp[c];
    float qx = posq[(size_t)wid * 2 + 0], qy = posq[(size_t)wid * 2 + 1];
    const float* pp = pts + ((size_t)b * NPTS + ii) * 2;
    in[CIN] = pp[0] - qx;
    in[CIN + 1] = pp[1] - qy;
  }
  // Phase B+C: hidden layer + transpose to LDS (wave-local, no barrier needed)
  float* hbase = &sHH[wv * 64 * HS];
#pragma unroll
  for (int h = 0; h < H; h += 4) {
    float vv[4];
#pragma unroll
    for (int j = 0; j < 4; ++j) {
      float a = sB1[h + j];
#pragma unroll
      for (int c = 0; c < CI2; ++c) a = fmaf(in[c], sW1t[(h + j) * W1P + c], a);
      vv[j] = fmaxf(a, 0.0f);
    }
    *(float4*)&hbase[lane * HS + h] = make_float4(vv[0], vv[1], vv[2], vv[3]);
  }
  // Phase D: second layer + masked max over neighbors
#pragma unroll
  for (int half = 0; half < COUT / 64; ++half) {
    const int o = half * 64 + lane;
    float w2r[H];
#pragma unroll
    for (int h = 0; h < H; ++h) w2r[h] = W2[h * COUT + o];
    const float b2o = b2[o];
    float m = -1e30f;
    for (int n = 0; n < 64; ++n) {
      const float4* hp = (const float4*)&hbase[n * HS];
      float a = b2o;
#pragma unroll
      for (int j = 0; j < H / 4; ++j) {
        float4 hv = hp[j];
        a = fmaf(hv.x, w2r[4 * j + 0], a);
        a = fmaf(hv.y, w2r[4 * j + 1], a);
        a = fmaf(hv.z, w2r[4 * j + 2], a);
        a = fmaf(hv.w, w2r[4 * j + 3], a);
      }
      a = ((vm >> n) & 1ULL) ? a : -1e9f;   // masked like reference (-BIG)
      m = fmaxf(m, a);
    }
    out[(size_t)wid * COUT + o] = m;
  }
}

// ---------------------------------------------------- global MLP (layer a)
__global__ __launch_bounds__(256) void u_kernel(
    const float* __restrict__ h2,     // [4096][128]
    const float* __restrict__ posq2,  // [4096][2]
    const float* __restrict__ W3a, const float* __restrict__ b3a,
    float* __restrict__ u) {          // [4096][128]
  const int p = blockIdx.x * 2 + (threadIdx.x >> 7);
  const int h = threadIdx.x & 127;
  const float* hp = h2 + (size_t)p * 128;
  float a = b3a[h];
  for (int c = 0; c < 128; ++c) a = fmaf(hp[c], W3a[c * 128 + h], a);
  a = fmaf(posq2[(size_t)p * 2 + 0], W3a[128 * 128 + h], a);
  a = fmaf(posq2[(size_t)p * 2 + 1], W3a[129 * 128 + h], a);
  u[(size_t)p * 128 + h] = fmaxf(a, 0.0f);
}

// ---------------------------------- global MLP (layer b) + partial max-pool
__global__ __launch_bounds__(256) void g_kernel(
    const float* __restrict__ u,      // [4096][128]
    const float* __restrict__ W3b, const float* __restrict__ b3b,
    float* __restrict__ part) {       // [64][256]
  __shared__ float su[64 * 128];
  const int bb = blockIdx.x;          // chunk of 64 consecutive points
  const float* up = u + (size_t)bb * 64 * 128;
  for (int j = threadIdx.x; j < 64 * 128; j += 256) su[j] = up[j];
  __syncthreads();
  const int o = threadIdx.x;
  float w[128];
#pragma unroll
  for (int h = 0; h < 128; ++h) w[h] = W3b[h * 256 + o];
  float m = -1e30f;
  for (int p = 0; p < 64; ++p) {
    float a = b3b[o];
    const float4* sp = (const float4*)&su[p * 128];
#pragma unroll
    for (int j = 0; j < 32; ++j) {
      float4 v = sp[j];
      a = fmaf(v.x, w[4 * j + 0], a);
      a = fmaf(v.y, w[4 * j + 1], a);
      a = fmaf(v.z, w[4 * j + 2], a);
      a = fmaf(v.w, w[4 * j + 3], a);
    }
    m = fmaxf(m, a);
  }
  part[(size_t)bb * 256 + o] = m;
}

// ------------------------------------------------------------------ head
__global__ __launch_bounds__(256) void head_kernel(
    const float* __restrict__ part,   // [64][256] (8 chunks per batch)
    const float* __restrict__ W4a, const float* __restrict__ b4a,
    const float* __restrict__ W4b, const float* __restrict__ b4b,
    float* __restrict__ out) {        // [8][1024]
  __shared__ float g[256], h4[256];
  const int b = blockIdx.x, t = threadIdx.x;
  float m = part[(size_t)(b * 8 + 0) * 256 + t];
  for (int c = 1; c < 8; ++c) m = fmaxf(m, part[(size_t)(b * 8 + c) * 256 + t]);
  g[t] = m;
  __syncthreads();
  float a = b4a[t];
  for (int c = 0; c < 256; ++c) a = fmaf(g[c], W4a[c * 256 + t], a);
  h4[t] = fmaxf(a, 0.0f);
  __syncthreads();
  for (int jj = 0; jj < 4; ++jj) {
    int o = t + jj * 256;
    float a2 = b4b[o];
    for (int c = 0; c < 256; ++c) a2 = fmaf(h4[c], W4b[c * 1024 + o], a2);
    out[(size_t)b * 1024 + o] = a2;
  }
}

// ------------------------------------------------------------------ launch
extern "C" void kernel_launch(void* const* d_in, const int* in_sizes, int n_in,
                              void* d_out, int out_size, void* d_ws, size_t ws_size,
                              hipStream_t stream) {
  (void)in_sizes; (void)n_in; (void)out_size; (void)ws_size;
  const float* x   = (const float*)d_in[0];
  const float* pos = (const float*)d_in[1];
  const float* w1a = (const float*)d_in[2];  const float* b1a = (const float*)d_in[3];
  const float* w1b = (const float*)d_in[4];  const float* b1b = (const float*)d_in[5];
  const float* w2a = (const float*)d_in[6];  const float* b2a = (const float*)d_in[7];
  const float* w2b = (const float*)d_in[8];  const float* b2b = (const float*)d_in[9];
  const float* w3a = (const float*)d_in[10]; const float* b3a = (const float*)d_in[11];
  const float* w3b = (const float*)d_in[12]; const float* b3b = (const float*)d_in[13];
  const float* w4a = (const float*)d_in[14]; const float* b4a = (const float*)d_in[15];
  const float* w4b = (const float*)d_in[16]; const float* b4b = (const float*)d_in[17];
  float* outp = (float*)d_out;

  char* ws = (char*)d_ws;
  size_t off = 0;
  float* posq1 = (float*)(ws + off); off += (size_t)8 * 2048 * 2 * 4;   // 128 KB
  float* posq2 = (float*)(ws + off); off += (size_t)8 * 512 * 2 * 4;    //  32 KB
  int*   nbr1  = (int*)  (ws + off); off += (size_t)16384 * 64 * 4;     //   4 MB
  int*   nbr2  = (int*)  (ws + off); off += (size_t)4096 * 64 * 4;      //   1 MB
  float* h1    = (float*)(ws + off); off += (size_t)16384 * 64 * 4;     //   4 MB
  float* h2    = (float*)(ws + off); off += (size_t)4096 * 128 * 4;     //   2 MB
  float* u3    = (float*)(ws + off); off += (size_t)4096 * 128 * 4;     //   2 MB
  float* part  = (float*)(ws + off); off += (size_t)64 * 256 * 4;       //  64 KB

  fps_fused_kernel<4096, 2048, 512, 512><<<dim3(8), dim3(512), 0, stream>>>(
      pos, posq1, posq2);
  nbr_kernel<64><<<dim3(4096), dim3(256), 0, stream>>>(pos, posq1, nbr1,
                                                       2048, 4096, 16384, 0.04f);
  conv_kernel<5, 32, 64, 4, 4096, 36, 8><<<dim3(4096), dim3(256), 0, stream>>>(
      x, pos, posq1, nbr1, w1a, b1a, w1b, b1b, h1, 2048);
  nbr_kernel<32><<<dim3(1024), dim3(256), 0, stream>>>(posq1, posq2, nbr2,
                                                       512, 2048, 4096, 0.16f);
  conv_kernel<64, 64, 128, 2, 2048, 68, 68><<<dim3(2048), dim3(128), 0, stream>>>(
      h1, posq1, posq2, nbr2, w2a, b2a, w2b, b2b, h2, 512);
  u_kernel<<<dim3(2048), dim3(256), 0, stream>>>(h2, posq2, w3a, b3a, u3);
  g_kernel<<<dim3(64), dim3(256), 0, stream>>>(u3, w3b, b3b, part);
  head_kernel<<<dim3(8), dim3(256), 0, stream>>>(part, w4a, b4a, w4b, b4b, outp);
}

// Round 8
// 2021.654 us; speedup vs baseline: 1.9791x; 1.1529x over previous
//
#include <hip/hip_runtime.h>

// PointNet++ forward (B=8, N=4096, D=2, F=5)
// sa1: FPS 4096->2048, r=0.2, MLP 7->32->64
// sa2: FPS 2048->512,  r=0.4, MLP 66->64->128
// sa3: MLP 130->128->256, global max
// head: MLP 256->256->1024
//
// Discrete selections (FPS argmax, top-64 neighbor sets) are reproduced
// bit-exactly vs XLA: distances use __fmul_rn/__fadd_rn (no FMA contraction),
// argmax = first max, top_k ties = lowest index first.

#define DPP_UMAX(u, ctrl)                                                      \
  do {                                                                         \
    unsigned _o = (unsigned)__builtin_amdgcn_update_dpp(0, (int)(u), (ctrl),   \
                                                        0xf, 0xf, true);       \
    (u) = ((u) > _o) ? (u) : _o;                                               \
  } while (0)

// One FPS stage, r2-proven inner loop (measured 527 ns/iter):
// points in registers (lane-contiguous: point = t*PPT+k) + LDS mirror
// srcx/srcy for the post-reduce broadcast coord lookup. Per-lane argmax
// tracks (val, idx) only; cross-wave exchange is a u64 key
// (dist_bits<<32)|~idx so ties pick the smallest point index. Winners are
// appended to the LDS list outx/outy (bulk global write happens outside).
template<int PPT, int T>
__device__ __forceinline__ void fps_stage(
    float (&xr)[PPT], float (&yr)[PPT], int Msel, int t,
    const float* srcx, const float* srcy,      // LDS mirror of stage points
    float* outx, float* outy,                  // LDS winner list (this stage)
    unsigned long long* sp /*[2*NW]*/) {
  constexpr int NW = T / 64;
  constexpr int HP = PPT / 2;
  float lx = srcx[0], ly = srcy[0];
  if (t == 0) { outx[0] = lx; outy[0] = ly; }
  float d[PPT];
#pragma unroll
  for (int k = 0; k < PPT; ++k) d[k] = 1e9f;

  for (int i = 1; i < Msel; ++i) {
    // distance update (exact: mul/mul/add, no fma)
#pragma unroll
    for (int k = 0; k < PPT; ++k) {
      float dx = xr[k] - lx, dy = yr[k] - ly;
      float dd = __fadd_rn(__fmul_rn(dx, dx), __fmul_rn(dy, dy));
      d[k] = fminf(d[k], dd);
    }
    // per-lane first-argmax (val, idx): two independent half-chains + merge
    float bvA = d[0]; int bkA = 0;
    float bvB = d[HP]; int bkB = HP;
#pragma unroll
    for (int k = 1; k < HP; ++k) {
      if (d[k] > bvA)      { bvA = d[k];      bkA = k; }
      if (d[HP + k] > bvB) { bvB = d[HP + k]; bkB = HP + k; }
    }
    float bv = bvA; int bk = bkA;
    if (bvB > bvA) { bv = bvB; bk = bkB; }     // tie keeps A = lower indices
    const int bp = t * PPT + bk;               // absolute point index
    // wave-level value max via DPP (VALU pipe)
    const unsigned mybits = __float_as_uint(bv);
    unsigned u = mybits;
    DPP_UMAX(u, 0x111);  // row_shr:1
    DPP_UMAX(u, 0x112);  // row_shr:2
    DPP_UMAX(u, 0x114);  // row_shr:4
    DPP_UMAX(u, 0x118);  // row_shr:8
    DPP_UMAX(u, 0x142);  // row_bcast:15
    DPP_UMAX(u, 0x143);  // row_bcast:31 -> lane63 = wave max
    const unsigned wvb = (unsigned)__builtin_amdgcn_readlane((int)u, 63);
    const unsigned long long tmask = __ballot(mybits == wvb);
    const int fl = (int)__builtin_ctzll(tmask);  // first lane = smallest idx
    const int wbp = __builtin_amdgcn_readlane(bp, fl);
    const int par = i & 1;
    if ((t & 63) == 0)
      sp[par * NW + (t >> 6)] =
          ((unsigned long long)wvb << 32) | (unsigned)(~wbp);
    __syncthreads();
    // cross-wave winner: serial scan of NW u64 slots (broadcast reads)
    const unsigned long long* sl = &sp[par * NW];
    unsigned long long best = sl[0];
#pragma unroll
    for (int j = 1; j < NW; ++j) {
      unsigned long long v = sl[j];
      best = (v > best) ? v : best;   // tie: larger ~idx == smaller idx
    }
    const int wi = (int)(~(unsigned)best);
    lx = srcx[wi]; ly = srcy[wi];     // broadcast LDS read (uniform address)
    if (t == 0) { outx[i] = lx; outy[i] = ly; }
    // no 2nd barrier: sp double-buffered by parity
  }
}

// Fused fps1 (N->M1) + fps2 (M1->M2); one block per batch, T=512 (8 waves).
template<int N, int M1, int M2, int T>
__global__ __launch_bounds__(T, 1) void fps_fused_kernel(
    const float* __restrict__ pos,    // [B][N][2]
    float* __restrict__ posq1,        // [B][M1][2]
    float* __restrict__ posq2) {      // [B][M2][2]
  constexpr int PPT  = N / T;
  constexpr int PPT2 = M1 / T;
  constexpr int NW   = T / 64;
  __shared__ float sx[N], sy[N];          // stage-1 point mirror
  __shared__ float wlx[M1], wly[M1];      // stage-1 winners = stage-2 points
  __shared__ float wl2x[M2], wl2y[M2];    // stage-2 winners
  __shared__ unsigned long long sp[2 * NW];
  const int b = blockIdx.x, t = threadIdx.x;
  float xr[PPT], yr[PPT];
  const float4* p4 = (const float4*)(pos + (size_t)b * N * 2 + (size_t)t * PPT * 2);
#pragma unroll
  for (int q = 0; q < PPT / 2; ++q) {
    float4 v = p4[q];
    xr[2 * q + 0] = v.x; yr[2 * q + 0] = v.y;
    xr[2 * q + 1] = v.z; yr[2 * q + 1] = v.w;
  }
#pragma unroll
  for (int k = 0; k < PPT; ++k) {
    int pt = t * PPT + k;
    sx[pt] = xr[k]; sy[pt] = yr[k];
  }
  __syncthreads();
  fps_stage<PPT, T>(xr, yr, M1, t, sx, sy, wlx, wly, sp);
  __syncthreads();                       // winner list complete
  for (int j = t; j < M1; j += T)        // bulk coalesced posq1
    ((float2*)posq1)[(size_t)b * M1 + j] = make_float2(wlx[j], wly[j]);
  float x2[PPT2], y2[PPT2];
#pragma unroll
  for (int k = 0; k < PPT2; ++k) { x2[k] = wlx[t * PPT2 + k]; y2[k] = wly[t * PPT2 + k]; }
  fps_stage<PPT2, T>(x2, y2, M2, t, wlx, wly, wl2x, wl2y, sp);
  __syncthreads();
  for (int j = t; j < M2; j += T)
    ((float2*)posq2)[(size_t)b * M2 + j] = make_float2(wl2x[j], wl2y[j]);
}

// ------------------------------------------------- radius top-64 neighbors
// One wave per query. Exact set of <=64 nearest in-radius points,
// matching lax.top_k(-d2) with lowest-index tie-break.
template<int CPL>   // candidate points per lane = NPTS/64
__global__ __launch_bounds__(256) void nbr_kernel(
    const float* __restrict__ pts,   // [B][NPTS][2]
    const float* __restrict__ posq,  // [total_q][2]
    int* __restrict__ nbr,           // [total_q][64], -1 = invalid
    int M, int NPTS, int total_q, float R2) {
  const int wid = blockIdx.x * 4 + (threadIdx.x >> 6);
  if (wid >= total_q) return;
  const int lane = threadIdx.x & 63;
  const int b = wid / M;
  const float qx = posq[(size_t)wid * 2 + 0], qy = posq[(size_t)wid * 2 + 1];
  const float* p = pts + (size_t)b * NPTS * 2;
  unsigned bits[CPL];
  int cnt = 0;
#pragma unroll
  for (int k = 0; k < CPL; ++k) {
    int pt = lane + (k << 6);
    float dx = p[pt * 2 + 0] - qx, dy = p[pt * 2 + 1] - qy;
    float dd = __fadd_rn(__fmul_rn(dx, dx), __fmul_rn(dy, dy));  // exact
    bool inr = (dd <= R2);
    bits[k] = inr ? __float_as_uint(dd) : 0xFFFFFFFFu;
    cnt += __popcll(__ballot(inr));
  }
  const unsigned long long below = (1ULL << lane) - 1ULL;
  if (cnt <= 64) {
    int base = 0;
#pragma unroll
    for (int k = 0; k < CPL; ++k) {
      bool s = (bits[k] != 0xFFFFFFFFu);
      unsigned long long m = __ballot(s);
      if (s) nbr[(size_t)wid * 64 + base + __popcll(m & below)] = lane + (k << 6);
      base += __popcll(m);
    }
    for (int j = base + lane; j < 64; j += 64) nbr[(size_t)wid * 64 + j] = -1;
  } else {
    // bisection on float bit pattern for exact 64th smallest d2
    unsigned lo = 0, hi = __float_as_uint(R2);
    while (lo < hi) {
      unsigned mid = lo + ((hi - lo) >> 1);
      int c = 0;
#pragma unroll
      for (int k = 0; k < CPL; ++k) c += __popcll(__ballot(bits[k] <= mid));
      if (c >= 64) hi = mid; else lo = mid + 1;
    }
    int cless = 0;
#pragma unroll
    for (int k = 0; k < CPL; ++k) cless += __popcll(__ballot(bits[k] < lo));
    const int need = 64 - cless;     // ties to take at cutoff, ascending index
    int base = 0, tiecnt = 0;
#pragma unroll
    for (int k = 0; k < CPL; ++k) {
      bool tie = (bits[k] == lo);
      unsigned long long tm = __ballot(tie);
      bool s = (bits[k] < lo) || (tie && (tiecnt + __popcll(tm & below)) < need);
      tiecnt += __popcll(tm);
      unsigned long long m = __ballot(s);
      if (s) nbr[(size_t)wid * 64 + base + __popcll(m & below)] = lane + (k << 6);
      base += __popcll(m);
    }
    // base == 64 exactly; no fill needed
  }
}

// ------------------------------------------------------------ PointConv
// Wave per query. Phase B: lane = neighbor, compute hidden (W1t broadcast
// from LDS). Phase C: transpose hidden into LDS. Phase D: lane = out channel,
// W2 column in VGPRs, max over neighbors is lane-local (no cross-lane reduce).
template<int CIN, int H, int COUT, int QPB, int NPTS, int HS, int W1P>
__global__ __launch_bounds__(64 * QPB) void conv_kernel(
    const float* __restrict__ x,     // [B][NPTS][CIN]
    const float* __restrict__ pts,   // [B][NPTS][2]
    const float* __restrict__ posq,  // [total_q][2]
    const int* __restrict__ nbr,     // [total_q][64]
    const float* __restrict__ W1, const float* __restrict__ b1,   // [CIN+2][H],[H]
    const float* __restrict__ W2, const float* __restrict__ b2,   // [H][COUT],[COUT]
    float* __restrict__ out,         // [total_q][COUT]
    int M) {
  constexpr int CI2 = CIN + 2;
  __shared__ float sW1t[H * W1P];    // transposed: [H][CI2 padded]
  __shared__ float sB1[H];
  __shared__ float sHH[QPB * 64 * HS];
  const int tid = threadIdx.x;
  for (int j = tid; j < CI2 * H; j += 64 * QPB) {
    int c = j / H, h = j - c * H;
    sW1t[h * W1P + c] = W1[j];
  }
  for (int j = tid; j < H; j += 64 * QPB) sB1[j] = b1[j];
  __syncthreads();
  const int wv = tid >> 6, lane = tid & 63;
  const int wid = blockIdx.x * QPB + wv;
  const int b = wid / M;
  // Phase A: gather neighbor features + relative position
  const int idx = nbr[(size_t)wid * 64 + lane];
  const unsigned long long vm = __ballot(idx >= 0);
  const int ii = (idx < 0) ? 0 : idx;
  float in[CI2];
  {
    const float* xp = x + ((size_t)b * NPTS + ii) * CIN;
#pragma unroll
    for (int c = 0; c < CIN; ++c) in[c] = xp[c];
    float qx = posq[(size_t)wid * 2 + 0], qy = posq[(size_t)wid * 2 + 1];
    const float* pp = pts + ((size_t)b * NPTS + ii) * 2;
    in[CIN] = pp[0] - qx;
    in[CIN + 1] = pp[1] - qy;
  }
  // Phase B+C: hidden layer + transpose to LDS (wave-local, no barrier needed)
  float* hbase = &sHH[wv * 64 * HS];
#pragma unroll
  for (int h = 0; h < H; h += 4) {
    float vv[4];
#pragma unroll
    for (int j = 0; j < 4; ++j) {
      float a = sB1[h + j];
#pragma unroll
      for (int c = 0; c < CI2; ++c) a = fmaf(in[c], sW1t[(h + j) * W1P + c], a);
      vv[j] = fmaxf(a, 0.0f);
    }
    *(float4*)&hbase[lane * HS + h] = make_float4(vv[0], vv[1], vv[2], vv[3]);
  }
  // Phase D: second layer + masked max over neighbors
#pragma unroll
  for (int half = 0; half < COUT / 64; ++half) {
    const int o = half * 64 + lane;
    float w2r[H];
#pragma unroll
    for (int h = 0; h < H; ++h) w2r[h] = W2[h * COUT + o];
    const float b2o = b2[o];
    float m = -1e30f;
    for (int n = 0; n < 64; ++n) {
      const float4* hp = (const float4*)&hbase[n * HS];
      float a = b2o;
#pragma unroll
      for (int j = 0; j < H / 4; ++j) {
        float4 hv = hp[j];
        a = fmaf(hv.x, w2r[4 * j + 0], a);
        a = fmaf(hv.y, w2r[4 * j + 1], a);
        a = fmaf(hv.z, w2r[4 * j + 2], a);
        a = fmaf(hv.w, w2r[4 * j + 3], a);
      }
      a = ((vm >> n) & 1ULL) ? a : -1e9f;   // masked like reference (-BIG)
      m = fmaxf(m, a);
    }
    out[(size_t)wid * COUT + o] = m;
  }
}

// ---------------------------------------------------- global MLP (layer a)
__global__ __launch_bounds__(256) void u_kernel(
    const float* __restrict__ h2,     // [4096][128]
    const float* __restrict__ posq2,  // [4096][2]
    const float* __restrict__ W3a, const float* __restrict__ b3a,
    float* __restrict__ u) {          // [4096][128]
  const int p = blockIdx.x * 2 + (threadIdx.x >> 7);
  const int h = threadIdx.x & 127;
  const float* hp = h2 + (size_t)p * 128;
  float a = b3a[h];
  for (int c = 0; c < 128; ++c) a = fmaf(hp[c], W3a[c * 128 + h], a);
  a = fmaf(posq2[(size_t)p * 2 + 0], W3a[128 * 128 + h], a);
  a = fmaf(posq2[(size_t)p * 2 + 1], W3a[129 * 128 + h], a);
  u[(size_t)p * 128 + h] = fmaxf(a, 0.0f);
}

// ---------------------------------- global MLP (layer b) + partial max-pool
__global__ __launch_bounds__(256) void g_kernel(
    const float* __restrict__ u,      // [4096][128]
    const float* __restrict__ W3b, const float* __restrict__ b3b,
    float* __restrict__ part) {       // [64][256]
  __shared__ float su[64 * 128];
  const int bb = blockIdx.x;          // chunk of 64 consecutive points
  const float* up = u + (size_t)bb * 64 * 128;
  for (int j = threadIdx.x; j < 64 * 128; j += 256) su[j] = up[j];
  __syncthreads();
  const int o = threadIdx.x;
  float w[128];
#pragma unroll
  for (int h = 0; h < 128; ++h) w[h] = W3b[h * 256 + o];
  float m = -1e30f;
  for (int p = 0; p < 64; ++p) {
    float a = b3b[o];
    const float4* sp = (const float4*)&su[p * 128];
#pragma unroll
    for (int j = 0; j < 32; ++j) {
      float4 v = sp[j];
      a = fmaf(v.x, w[4 * j + 0], a);
      a = fmaf(v.y, w[4 * j + 1], a);
      a = fmaf(v.z, w[4 * j + 2], a);
      a = fmaf(v.w, w[4 * j + 3], a);
    }
    m = fmaxf(m, a);
  }
  part[(size_t)bb * 256 + o] = m;
}

// ------------------------------------------------------------------ head
__global__ __launch_bounds__(256) void head_kernel(
    const float* __restrict__ part,   // [64][256] (8 chunks per batch)
    const float* __restrict__ W4a, const float* __restrict__ b4a,
    const float* __restrict__ W4b, const float* __restrict__ b4b,
    float* __restrict__ out) {        // [8][1024]
  __shared__ float g[256], h4[256];
  const int b = blockIdx.x, t = threadIdx.x;
  float m = part[(size_t)(b * 8 + 0) * 256 + t];
  for (int c = 1; c < 8; ++c) m = fmaxf(m, part[(size_t)(b * 8 + c) * 256 + t]);
  g[t] = m;
  __syncthreads();
  float a = b4a[t];
  for (int c = 0; c < 256; ++c) a = fmaf(g[c], W4a[c * 256 + t], a);
  h4[t] = fmaxf(a, 0.0f);
  __syncthreads();
  for (int jj = 0; jj < 4; ++jj) {
    int o = t + jj * 256;
    float a2 = b4b[o];
    for (int c = 0; c < 256; ++c) a2 = fmaf(h4[c], W4b[c * 1024 + o], a2);
    out[(size_t)b * 1024 + o] = a2;
  }
}

// ------------------------------------------------------------------ launch
extern "C" void kernel_launch(void* const* d_in, const int* in_sizes, int n_in,
                              void* d_out, int out_size, void* d_ws, size_t ws_size,
                              hipStream_t stream) {
  (void)in_sizes; (void)n_in; (void)out_size; (void)ws_size;
  const float* x   = (const float*)d_in[0];
  const float* pos = (const float*)d_in[1];
  const float* w1a = (const float*)d_in[2];  const float* b1a = (const float*)d_in[3];
  const float* w1b = (const float*)d_in[4];  const float* b1b = (const float*)d_in[5];
  const float* w2a = (const float*)d_in[6];  const float* b2a = (const float*)d_in[7];
  const float* w2b = (const float*)d_in[8];  const float* b2b = (const float*)d_in[9];
  const float* w3a = (const float*)d_in[10]; const float* b3a = (const float*)d_in[11];
  const float* w3b = (const float*)d_in[12]; const float* b3b = (const float*)d_in[13];
  const float* w4a = (const float*)d_in[14]; const float* b4a = (const float*)d_in[15];
  const float* w4b = (const float*)d_in[16]; const float* b4b = (const float*)d_in[17];
  float* outp = (float*)d_out;

  char* ws = (char*)d_ws;
  size_t off = 0;
  float* posq1 = (float*)(ws + off); off += (size_t)8 * 2048 * 2 * 4;   // 128 KB
  float* posq2 = (float*)(ws + off); off += (size_t)8 * 512 * 2 * 4;    //  32 KB
  int*   nbr1  = (int*)  (ws + off); off += (size_t)16384 * 64 * 4;     //   4 MB
  int*   nbr2  = (int*)  (ws + off); off += (size_t)4096 * 64 * 4;      //   1 MB
  float* h1    = (float*)(ws + off); off += (size_t)16384 * 64 * 4;     //   4 MB
  float* h2    = (float*)(ws + off); off += (size_t)4096 * 128 * 4;     //   2 MB
  float* u3    = (float*)(ws + off); off += (size_t)4096 * 128 * 4;     //   2 MB
  float* part  = (float*)(ws + off); off += (size_t)64 * 256 * 4;       //  64 KB

  fps_fused_kernel<4096, 2048, 512, 512><<<dim3(8), dim3(512), 0, stream>>>(
      pos, posq1, posq2);
  nbr_kernel<64><<<dim3(4096), dim3(256), 0, stream>>>(pos, posq1, nbr1,
                                                       2048, 4096, 16384, 0.04f);
  conv_kernel<5, 32, 64, 4, 4096, 36, 8><<<dim3(4096), dim3(256), 0, stream>>>(
      x, pos, posq1, nbr1, w1a, b1a, w1b, b1b, h1, 2048);
  nbr_kernel<32><<<dim3(1024), dim3(256), 0, stream>>>(posq1, posq2, nbr2,
                                                       512, 2048, 4096, 0.16f);
  conv_kernel<64, 64, 128, 2, 2048, 68, 68><<<dim3(2048), dim3(128), 0, stream>>>(
      h1, posq1, posq2, nbr2, w2a, b2a, w2b, b2b, h2, 512);
  u_kernel<<<dim3(2048), dim3(256), 0, stream>>>(h2, posq2, w3a, b3a, u3);
  g_kernel<<<dim3(64), dim3(256), 0, stream>>>(u3, w3b, b3b, part);
  head_kernel<<<dim3(8), dim3(256), 0, stream>>>(part, w4a, b4a, w4b, b4b, outp);
}

// Round 9
// 2000.775 us; speedup vs baseline: 1.9998x; 1.0104x over previous
//
#include <hip/hip_runtime.h>
#include <hip/hip_cooperative_groups.h>

namespace cg = cooperative_groups;

// PointNet++ forward (B=8, N=4096, D=2, F=5)
// sa1: FPS 4096->2048, r=0.2, MLP 7->32->64
// sa2: FPS 2048->512,  r=0.4, MLP 66->64->128
// sa3: MLP 130->128->256, global max
// head: MLP 256->256->1024
//
// Discrete selections (FPS argmax, top-64 neighbor sets) are reproduced
// bit-exactly vs XLA: distances use __fmul_rn/__fadd_rn (no FMA contraction),
// argmax = first max, top_k ties = lowest index first.

#define DPP_UMAX(u, ctrl)                                                      \
  do {                                                                         \
    unsigned _o = (unsigned)__builtin_amdgcn_update_dpp(0, (int)(u), (ctrl),   \
                                                        0xf, 0xf, true);       \
    (u) = ((u) > _o) ? (u) : _o;                                               \
  } while (0)

// One FPS stage (r8-proven, 517 ns/iter): points in registers
// (lane-contiguous: point = t*PPT+k) + LDS mirror srcx/srcy for the
// post-reduce broadcast coord lookup. Per-lane argmax tracks (val, idx);
// cross-wave exchange key = (dist_bits<<32)|~idx (ties -> smallest index).
template<int PPT, int T>
__device__ __forceinline__ void fps_stage(
    float (&xr)[PPT], float (&yr)[PPT], int Msel, int t,
    const float* srcx, const float* srcy,      // LDS mirror of stage points
    float* outx, float* outy,                  // LDS winner list (this stage)
    unsigned long long* sp /*[2*NW]*/) {
  constexpr int NW = T / 64;
  constexpr int HP = PPT / 2;
  float lx = srcx[0], ly = srcy[0];
  if (t == 0) { outx[0] = lx; outy[0] = ly; }
  float d[PPT];
#pragma unroll
  for (int k = 0; k < PPT; ++k) d[k] = 1e9f;

  for (int i = 1; i < Msel; ++i) {
#pragma unroll
    for (int k = 0; k < PPT; ++k) {
      float dx = xr[k] - lx, dy = yr[k] - ly;
      float dd = __fadd_rn(__fmul_rn(dx, dx), __fmul_rn(dy, dy));
      d[k] = fminf(d[k], dd);
    }
    float bvA = d[0]; int bkA = 0;
    float bvB = d[HP]; int bkB = HP;
#pragma unroll
    for (int k = 1; k < HP; ++k) {
      if (d[k] > bvA)      { bvA = d[k];      bkA = k; }
      if (d[HP + k] > bvB) { bvB = d[HP + k]; bkB = HP + k; }
    }
    float bv = bvA; int bk = bkA;
    if (bvB > bvA) { bv = bvB; bk = bkB; }     // tie keeps A = lower indices
    const int bp = t * PPT + bk;
    const unsigned mybits = __float_as_uint(bv);
    unsigned u = mybits;
    DPP_UMAX(u, 0x111);  // row_shr:1
    DPP_UMAX(u, 0x112);  // row_shr:2
    DPP_UMAX(u, 0x114);  // row_shr:4
    DPP_UMAX(u, 0x118);  // row_shr:8
    DPP_UMAX(u, 0x142);  // row_bcast:15
    DPP_UMAX(u, 0x143);  // row_bcast:31 -> lane63 = wave max
    const unsigned wvb = (unsigned)__builtin_amdgcn_readlane((int)u, 63);
    const unsigned long long tmask = __ballot(mybits == wvb);
    const int fl = (int)__builtin_ctzll(tmask);
    const int wbp = __builtin_amdgcn_readlane(bp, fl);
    const int par = i & 1;
    if ((t & 63) == 0)
      sp[par * NW + (t >> 6)] =
          ((unsigned long long)wvb << 32) | (unsigned)(~wbp);
    __syncthreads();
    const unsigned long long* sl = &sp[par * NW];
    unsigned long long best = sl[0];
#pragma unroll
    for (int j = 1; j < NW; ++j) {
      unsigned long long v = sl[j];
      best = (v > best) ? v : best;
    }
    const int wi = (int)(~(unsigned)best);
    lx = srcx[wi]; ly = srcy[wi];
    if (t == 0) { outx[i] = lx; outy[i] = ly; }
  }
}

// Cooperative mega-kernel: blocks 0-7 do FPS (stage1, sync, stage2); blocks
// 8-255 do fused nbr1+conv1 after the grid sync, overlapping FPS stage 2.
__global__ __launch_bounds__(512) void mega_kernel(
    const float* __restrict__ pos,   // [8][4096][2]
    const float* __restrict__ xin,   // [8][4096][5]
    float* __restrict__ posq1,       // [8][2048][2]
    float* __restrict__ posq2,       // [8][512][2]
    float* __restrict__ h1,          // [16384][64]
    const float* __restrict__ W1, const float* __restrict__ B1,  // [7][32],[32]
    const float* __restrict__ W2, const float* __restrict__ B2)  // [32][64],[64]
{
  constexpr int N = 4096, M1 = 2048, M2 = 512, T = 512;
  constexpr int PPT = N / T, PPT2 = M1 / T, NW = T / 64;
  constexpr int H = 32, CI2 = 7, HS = 36, W1P = 8;
  __shared__ union {
    struct {
      float sx[N], sy[N];
      float wlx[M1], wly[M1];
      float wl2x[M2], wl2y[M2];
      unsigned long long sp[2 * NW];
    } f;                                        // 53.4 KB
    struct {
      float sW1t[H * W1P];
      float sB1[H];
      float sHH[8 * 64 * HS];
      int   sNbr[8][64];
    } c;                                        // 76.9 KB
  } sh;
  const int bid = blockIdx.x, t = threadIdx.x;
  cg::grid_group grid = cg::this_grid();

  float xr[PPT], yr[PPT];
  if (bid < 8) {
    // ---------------- FPS stage 1 (batch = bid)
    const int b = bid;
    const float4* p4 =
        (const float4*)(pos + (size_t)b * N * 2 + (size_t)t * PPT * 2);
#pragma unroll
    for (int q = 0; q < PPT / 2; ++q) {
      float4 v = p4[q];
      xr[2 * q + 0] = v.x; yr[2 * q + 0] = v.y;
      xr[2 * q + 1] = v.z; yr[2 * q + 1] = v.w;
    }
#pragma unroll
    for (int k = 0; k < PPT; ++k) {
      int pt = t * PPT + k;
      sh.f.sx[pt] = xr[k]; sh.f.sy[pt] = yr[k];
    }
    __syncthreads();
    fps_stage<PPT, T>(xr, yr, M1, t, sh.f.sx, sh.f.sy, sh.f.wlx, sh.f.wly,
                      sh.f.sp);
    __syncthreads();
    for (int j = t; j < M1; j += T)
      ((float2*)posq1)[(size_t)b * M1 + j] =
          make_float2(sh.f.wlx[j], sh.f.wly[j]);
    __threadfence();
  }
  grid.sync();

  if (bid < 8) {
    // ---------------- FPS stage 2 (overlaps conv1 on other blocks)
    const int b = bid;
    float x2[PPT2], y2[PPT2];
#pragma unroll
    for (int k = 0; k < PPT2; ++k) {
      x2[k] = sh.f.wlx[t * PPT2 + k];
      y2[k] = sh.f.wly[t * PPT2 + k];
    }
    fps_stage<PPT2, T>(x2, y2, M2, t, sh.f.wlx, sh.f.wly, sh.f.wl2x, sh.f.wl2y,
                       sh.f.sp);
    __syncthreads();
    for (int j = t; j < M2; j += T)
      ((float2*)posq2)[(size_t)b * M2 + j] =
          make_float2(sh.f.wl2x[j], sh.f.wl2y[j]);
  } else {
    // ---------------- fused nbr1 + conv1, wave-per-query, grid-stride
    for (int j = t; j < CI2 * H; j += T) {
      int cc = j / H, hh = j - cc * H;
      sh.c.sW1t[hh * W1P + cc] = W1[j];
    }
    for (int j = t; j < H; j += T) sh.c.sB1[j] = B1[j];
    __syncthreads();
    const int wv = t >> 6, lane = t & 63;
    const unsigned long long below = (1ULL << lane) - 1ULL;
    float* hbase = &sh.c.sHH[wv * 64 * HS];
    int* snb = sh.c.sNbr[wv];
    for (int wid = (bid - 8) * 8 + wv; wid < 16384; wid += 248 * 8) {
      const int b = wid >> 11;
      const float qx = posq1[2 * wid + 0], qy = posq1[2 * wid + 1];
      const float* p = pos + (size_t)b * N * 2;
      snb[lane] = -1;
      unsigned bits[64];
      int cnt = 0;
#pragma unroll
      for (int k = 0; k < 64; ++k) {
        int pt = lane + (k << 6);
        float dx = p[pt * 2 + 0] - qx, dy = p[pt * 2 + 1] - qy;
        float dd = __fadd_rn(__fmul_rn(dx, dx), __fmul_rn(dy, dy));
        bool inr = (dd <= 0.04f);
        bits[k] = inr ? __float_as_uint(dd) : 0xFFFFFFFFu;
        cnt += __popcll(__ballot(inr));
      }
      if (cnt <= 64) {
        int base = 0;
#pragma unroll
        for (int k = 0; k < 64; ++k) {
          bool s = (bits[k] != 0xFFFFFFFFu);
          unsigned long long m = __ballot(s);
          if (s) snb[base + __popcll(m & below)] = lane + (k << 6);
          base += __popcll(m);
        }
      } else {
        unsigned lo = 0, hi = __float_as_uint(0.04f);
        while (lo < hi) {
          unsigned mid = lo + ((hi - lo) >> 1);
          int c = 0;
#pragma unroll
          for (int k = 0; k < 64; ++k) c += __popcll(__ballot(bits[k] <= mid));
          if (c >= 64) hi = mid; else lo = mid + 1;
        }
        int cless = 0;
#pragma unroll
        for (int k = 0; k < 64; ++k) cless += __popcll(__ballot(bits[k] < lo));
        const int need = 64 - cless;
        int base = 0, tiecnt = 0;
#pragma unroll
        for (int k = 0; k < 64; ++k) {
          bool tie = (bits[k] == lo);
          unsigned long long tm = __ballot(tie);
          bool s = (bits[k] < lo) ||
                   (tie && (tiecnt + __popcll(tm & below)) < need);
          tiecnt += __popcll(tm);
          unsigned long long m = __ballot(s);
          if (s) snb[base + __popcll(m & below)] = lane + (k << 6);
          base += __popcll(m);
        }
      }
      const int idx = snb[lane];          // in-wave LDS exchange (in-order pipe)
      const unsigned long long vm = __ballot(idx >= 0);
      const int ii = (idx < 0) ? 0 : idx;
      float in[CI2];
      {
        const float* xp = xin + ((size_t)b * N + ii) * 5;
#pragma unroll
        for (int c = 0; c < 5; ++c) in[c] = xp[c];
        const float* pp = p + (size_t)ii * 2;
        in[5] = pp[0] - qx;
        in[6] = pp[1] - qy;
      }
#pragma unroll
      for (int h = 0; h < H; h += 4) {
        float vv[4];
#pragma unroll
        for (int j = 0; j < 4; ++j) {
          float a = sh.c.sB1[h + j];
#pragma unroll
          for (int c = 0; c < CI2; ++c)
            a = fmaf(in[c], sh.c.sW1t[(h + j) * W1P + c], a);
          vv[j] = fmaxf(a, 0.0f);
        }
        *(float4*)&hbase[lane * HS + h] = make_float4(vv[0], vv[1], vv[2], vv[3]);
      }
      const int o = lane;
      float w2r[H];
#pragma unroll
      for (int h = 0; h < H; ++h) w2r[h] = W2[h * 64 + o];
      const float b2o = B2[o];
      float m = -1e30f;
      for (int n = 0; n < 64; ++n) {
        const float4* hp = (const float4*)&hbase[n * HS];
        float a = b2o;
#pragma unroll
        for (int j = 0; j < H / 4; ++j) {
          float4 hv = hp[j];
          a = fmaf(hv.x, w2r[4 * j + 0], a);
          a = fmaf(hv.y, w2r[4 * j + 1], a);
          a = fmaf(hv.z, w2r[4 * j + 2], a);
          a = fmaf(hv.w, w2r[4 * j + 3], a);
        }
        a = ((vm >> n) & 1ULL) ? a : -1e9f;
        m = fmaxf(m, a);
      }
      h1[(size_t)wid * 64 + o] = m;
    }
  }
}

// ------------------------------------------------- radius top-64 neighbors
template<int CPL>
__global__ __launch_bounds__(256) void nbr_kernel(
    const float* __restrict__ pts, const float* __restrict__ posq,
    int* __restrict__ nbr, int M, int NPTS, int total_q, float R2) {
  const int wid = blockIdx.x * 4 + (threadIdx.x >> 6);
  if (wid >= total_q) return;
  const int lane = threadIdx.x & 63;
  const int b = wid / M;
  const float qx = posq[(size_t)wid * 2 + 0], qy = posq[(size_t)wid * 2 + 1];
  const float* p = pts + (size_t)b * NPTS * 2;
  unsigned bits[CPL];
  int cnt = 0;
#pragma unroll
  for (int k = 0; k < CPL; ++k) {
    int pt = lane + (k << 6);
    float dx = p[pt * 2 + 0] - qx, dy = p[pt * 2 + 1] - qy;
    float dd = __fadd_rn(__fmul_rn(dx, dx), __fmul_rn(dy, dy));
    bool inr = (dd <= R2);
    bits[k] = inr ? __float_as_uint(dd) : 0xFFFFFFFFu;
    cnt += __popcll(__ballot(inr));
  }
  const unsigned long long below = (1ULL << lane) - 1ULL;
  if (cnt <= 64) {
    int base = 0;
#pragma unroll
    for (int k = 0; k < CPL; ++k) {
      bool s = (bits[k] != 0xFFFFFFFFu);
      unsigned long long m = __ballot(s);
      if (s) nbr[(size_t)wid * 64 + base + __popcll(m & below)] = lane + (k << 6);
      base += __popcll(m);
    }
    for (int j = base + lane; j < 64; j += 64) nbr[(size_t)wid * 64 + j] = -1;
  } else {
    unsigned lo = 0, hi = __float_as_uint(R2);
    while (lo < hi) {
      unsigned mid = lo + ((hi - lo) >> 1);
      int c = 0;
#pragma unroll
      for (int k = 0; k < CPL; ++k) c += __popcll(__ballot(bits[k] <= mid));
      if (c >= 64) hi = mid; else lo = mid + 1;
    }
    int cless = 0;
#pragma unroll
    for (int k = 0; k < CPL; ++k) cless += __popcll(__ballot(bits[k] < lo));
    const int need = 64 - cless;
    int base = 0, tiecnt = 0;
#pragma unroll
    for (int k = 0; k < CPL; ++k) {
      bool tie = (bits[k] == lo);
      unsigned long long tm = __ballot(tie);
      bool s = (bits[k] < lo) || (tie && (tiecnt + __popcll(tm & below)) < need);
      tiecnt += __popcll(tm);
      unsigned long long m = __ballot(s);
      if (s) nbr[(size_t)wid * 64 + base + __popcll(m & below)] = lane + (k << 6);
      base += __popcll(m);
    }
  }
}

// ------------------------------------------------------------ PointConv
template<int CIN, int H, int COUT, int QPB, int NPTS, int HS, int W1P>
__global__ __launch_bounds__(64 * QPB) void conv_kernel(
    const float* __restrict__ x, const float* __restrict__ pts,
    const float* __restrict__ posq, const int* __restrict__ nbr,
    const float* __restrict__ W1, const float* __restrict__ b1,
    const float* __restrict__ W2, const float* __restrict__ b2,
    float* __restrict__ out, int M) {
  constexpr int CI2 = CIN + 2;
  __shared__ float sW1t[H * W1P];
  __shared__ float sB1[H];
  __shared__ float sHH[QPB * 64 * HS];
  const int tid = threadIdx.x;
  for (int j = tid; j < CI2 * H; j += 64 * QPB) {
    int c = j / H, h = j - c * H;
    sW1t[h * W1P + c] = W1[j];
  }
  for (int j = tid; j < H; j += 64 * QPB) sB1[j] = b1[j];
  __syncthreads();
  const int wv = tid >> 6, lane = tid & 63;
  const int wid = blockIdx.x * QPB + wv;
  const int b = wid / M;
  const int idx = nbr[(size_t)wid * 64 + lane];
  const unsigned long long vm = __ballot(idx >= 0);
  const int ii = (idx < 0) ? 0 : idx;
  float in[CI2];
  {
    const float* xp = x + ((size_t)b * NPTS + ii) * CIN;
#pragma unroll
    for (int c = 0; c < CIN; ++c) in[c] = xp[c];
    float qx = posq[(size_t)wid * 2 + 0], qy = posq[(size_t)wid * 2 + 1];
    const float* pp = pts + ((size_t)b * NPTS + ii) * 2;
    in[CIN] = pp[0] - qx;
    in[CIN + 1] = pp[1] - qy;
  }
  float* hbase = &sHH[wv * 64 * HS];
#pragma unroll
  for (int h = 0; h < H; h += 4) {
    float vv[4];
#pragma unroll
    for (int j = 0; j < 4; ++j) {
      float a = sB1[h + j];
#pragma unroll
      for (int c = 0; c < CI2; ++c) a = fmaf(in[c], sW1t[(h + j) * W1P + c], a);
      vv[j] = fmaxf(a, 0.0f);
    }
    *(float4*)&hbase[lane * HS + h] = make_float4(vv[0], vv[1], vv[2], vv[3]);
  }
#pragma unroll
  for (int half = 0; half < COUT / 64; ++half) {
    const int o = half * 64 + lane;
    float w2r[H];
#pragma unroll
    for (int h = 0; h < H; ++h) w2r[h] = W2[h * COUT + o];
    const float b2o = b2[o];
    float m = -1e30f;
    for (int n = 0; n < 64; ++n) {
      const float4* hp = (const float4*)&hbase[n * HS];
      float a = b2o;
#pragma unroll
      for (int j = 0; j < H / 4; ++j) {
        float4 hv = hp[j];
        a = fmaf(hv.x, w2r[4 * j + 0], a);
        a = fmaf(hv.y, w2r[4 * j + 1], a);
        a = fmaf(hv.z, w2r[4 * j + 2], a);
        a = fmaf(hv.w, w2r[4 * j + 3], a);
      }
      a = ((vm >> n) & 1ULL) ? a : -1e9f;
      m = fmaxf(m, a);
    }
    out[(size_t)wid * COUT + o] = m;
  }
}

// ---------------------------------------------------- global MLP (layer a)
__global__ __launch_bounds__(256) void u_kernel(
    const float* __restrict__ h2, const float* __restrict__ posq2,
    const float* __restrict__ W3a, const float* __restrict__ b3a,
    float* __restrict__ u) {
  const int p = blockIdx.x * 2 + (threadIdx.x >> 7);
  const int h = threadIdx.x & 127;
  const float* hp = h2 + (size_t)p * 128;
  float a = b3a[h];
  for (int c = 0; c < 128; ++c) a = fmaf(hp[c], W3a[c * 128 + h], a);
  a = fmaf(posq2[(size_t)p * 2 + 0], W3a[128 * 128 + h], a);
  a = fmaf(posq2[(size_t)p * 2 + 1], W3a[129 * 128 + h], a);
  u[(size_t)p * 128 + h] = fmaxf(a, 0.0f);
}

// ---------------------------------- global MLP (layer b) + partial max-pool
__global__ __launch_bounds__(256) void g_kernel(
    const float* __restrict__ u, const float* __restrict__ W3b,
    const float* __restrict__ b3b, float* __restrict__ part) {
  __shared__ float su[64 * 128];
  const int bb = blockIdx.x;
  const float* up = u + (size_t)bb * 64 * 128;
  for (int j = threadIdx.x; j < 64 * 128; j += 256) su[j] = up[j];
  __syncthreads();
  const int o = threadIdx.x;
  float w[128];
#pragma unroll
  for (int h = 0; h < 128; ++h) w[h] = W3b[h * 256 + o];
  float m = -1e30f;
  for (int p = 0; p < 64; ++p) {
    float a = b3b[o];
    const float4* sp = (const float4*)&su[p * 128];
#pragma unroll
    for (int j = 0; j < 32; ++j) {
      float4 v = sp[j];
      a = fmaf(v.x, w[4 * j + 0], a);
      a = fmaf(v.y, w[4 * j + 1], a);
      a = fmaf(v.z, w[4 * j + 2], a);
      a = fmaf(v.w, w[4 * j + 3], a);
    }
    m = fmaxf(m, a);
  }
  part[(size_t)bb * 256 + o] = m;
}

// ------------------------------------------------------------------ head
__global__ __launch_bounds__(256) void head_kernel(
    const float* __restrict__ part, const float* __restrict__ W4a,
    const float* __restrict__ b4a, const float* __restrict__ W4b,
    const float* __restrict__ b4b, float* __restrict__ out) {
  __shared__ float g[256], h4[256];
  const int b = blockIdx.x, t = threadIdx.x;
  float m = part[(size_t)(b * 8 + 0) * 256 + t];
  for (int c = 1; c < 8; ++c) m = fmaxf(m, part[(size_t)(b * 8 + c) * 256 + t]);
  g[t] = m;
  __syncthreads();
  float a = b4a[t];
  for (int c = 0; c < 256; ++c) a = fmaf(g[c], W4a[c * 256 + t], a);
  h4[t] = fmaxf(a, 0.0f);
  __syncthreads();
  for (int jj = 0; jj < 4; ++jj) {
    int o = t + jj * 256;
    float a2 = b4b[o];
    for (int c = 0; c < 256; ++c) a2 = fmaf(h4[c], W4b[c * 1024 + o], a2);
    out[(size_t)b * 1024 + o] = a2;
  }
}

// ------------------------------------------------------------------ launch
extern "C" void kernel_launch(void* const* d_in, const int* in_sizes, int n_in,
                              void* d_out, int out_size, void* d_ws, size_t ws_size,
                              hipStream_t stream) {
  (void)in_sizes; (void)n_in; (void)out_size; (void)ws_size;
  const float* x   = (const float*)d_in[0];
  const float* pos = (const float*)d_in[1];
  const float* w1a = (const float*)d_in[2];  const float* b1a = (const float*)d_in[3];
  const float* w1b = (const float*)d_in[4];  const float* b1b = (const float*)d_in[5];
  const float* w2a = (const float*)d_in[6];  const float* b2a = (const float*)d_in[7];
  const float* w2b = (const float*)d_in[8];  const float* b2b = (const float*)d_in[9];
  const float* w3a = (const float*)d_in[10]; const float* b3a = (const float*)d_in[11];
  const float* w3b = (const float*)d_in[12]; const float* b3b = (const float*)d_in[13];
  const float* w4a = (const float*)d_in[14]; const float* b4a = (const float*)d_in[15];
  const float* w4b = (const float*)d_in[16]; const float* b4b = (const float*)d_in[17];
  float* outp = (float*)d_out;

  char* ws = (char*)d_ws;
  size_t off = 0;
  float* posq1 = (float*)(ws + off); off += (size_t)8 * 2048 * 2 * 4;
  float* posq2 = (float*)(ws + off); off += (size_t)8 * 512 * 2 * 4;
  int*   nbr2  = (int*)  (ws + off); off += (size_t)4096 * 64 * 4;
  float* h1    = (float*)(ws + off); off += (size_t)16384 * 64 * 4;
  float* h2    = (float*)(ws + off); off += (size_t)4096 * 128 * 4;
  float* u3    = (float*)(ws + off); off += (size_t)4096 * 128 * 4;
  float* part  = (float*)(ws + off); off += (size_t)64 * 256 * 4;

  void* kargs[] = {(void*)&pos, (void*)&x, (void*)&posq1, (void*)&posq2,
                   (void*)&h1, (void*)&w1a, (void*)&b1a, (void*)&w1b,
                   (void*)&b1b};
  hipLaunchCooperativeKernel((void*)mega_kernel, dim3(256), dim3(512), kargs,
                             0, stream);
  nbr_kernel<32><<<dim3(1024), dim3(256), 0, stream>>>(posq1, posq2, nbr2,
                                                       512, 2048, 4096, 0.16f);
  conv_kernel<64, 64, 128, 2, 2048, 68, 68><<<dim3(2048), dim3(128), 0, stream>>>(
      h1, posq1, posq2, nbr2, w2a, b2a, w2b, b2b, h2, 512);
  u_kernel<<<dim3(2048), dim3(256), 0, stream>>>(h2, posq2, w3a, b3a, u3);
  g_kernel<<<dim3(64), dim3(256), 0, stream>>>(u3, w3b, b3b, part);
  head_kernel<<<dim3(8), dim3(256), 0, stream>>>(part, w4a, b4a, w4b, b4b, outp);
}